// Round 1
// baseline (1511.200 us; speedup 1.0000x reference)
//
#include <hip/hip_runtime.h>
#include <cstddef>

namespace {
constexpr int kBatch = 32, kH = 512, kW = 512, kCin = 6, kCout = 16, kFs = 5;
constexpr int kOH = kH - kFs + 1, kOW = kW - kFs + 1;  // 508
constexpr int kTile = 32;                 // output tile per block (32x32)
constexpr int kIT = kTile + kFs - 1;      // 36 input rows/cols with halo
constexpr int kRowB = kIT * kCin;         // 216 floats per LDS input row
constexpr int kWElems = kFs * kFs * kCin * kCout;  // 2400
constexpr int kRowF4 = kRowB / 4;         // 54 float4 per input row
constexpr int kTotF4 = kIT * kRowF4;      // 1944 float4 per tile

// Per-input-channel list of the 10 structurally-nonzero output channels.
// Derived from the assemble table:
//   o in 0..5  : connected iff (c-o) mod 6 in {0,1,2}  -> o in {c, c-1, c-2}
//   o in 6..11 : connected iff (c-k) mod 6 in {0,1,2,3}-> k in {c..c-3}
//   o in 12..14: k with (c-k) mod 6 in {0,1,3,4}
//   o == 15    : always
__device__ constexpr int kSet[6][10] = {
    {0, 4, 5, 6, 9, 10, 11, 12, 14, 15},
    {0, 1, 5, 6, 7, 10, 11, 12, 13, 15},
    {0, 1, 2, 6, 7, 8, 11, 13, 14, 15},
    {1, 2, 3, 6, 7, 8, 9, 12, 14, 15},
    {2, 3, 4, 7, 8, 9, 10, 12, 13, 15},
    {3, 4, 5, 8, 9, 10, 11, 13, 14, 15},
};
}  // namespace

// Assemble dense [5][5][6][16] kernel (o contiguous) from the sparse tables.
__global__ void assemble_weights(const float* __restrict__ w3,
                                 const float* __restrict__ w4,
                                 const float* __restrict__ w44,
                                 const float* __restrict__ w6,
                                 float* __restrict__ wd) {
  int i = blockIdx.x * blockDim.x + threadIdx.x;
  if (i >= kWElems) return;
  int o = i & 15;                 // output channel
  int c = (i >> 4) % kCin;        // input channel
  int p = i / (kCout * kCin);     // ky*5+kx
  float val = 0.f;
  if (o < 6) {
    int m = (c - o + 6) % 6;
    if (m < 3) val = w3[(p * 3 + m) * 6 + o];
  } else if (o < 12) {
    int k = o - 6;
    int m = (c - k + 6) % 6;
    if (m < 4) val = w4[(p * 4 + m) * 6 + k];
  } else if (o < 15) {
    int k = o - 12;
    int d = (c - k + 6) % 6;
    int m = (d == 0) ? 0 : (d == 1) ? 1 : (d == 3) ? 2 : (d == 4) ? 3 : -1;
    if (m >= 0) val = w44[(p * 4 + m) * 3 + k];
  } else {
    val = w6[p * 6 + c];
  }
  wd[i] = val;
}

__global__ __launch_bounds__(256) void conv_sparse(
    const float* __restrict__ in, const float* __restrict__ wd,
    const float* __restrict__ bias, float* __restrict__ out) {
  __shared__ float s_in[kIT * kRowB];  // 36*216 = 7776 floats (31.1 KB)

  const int t = threadIdx.x;
  const int bx0 = blockIdx.x * kTile, by0 = blockIdx.y * kTile;
  const int b = blockIdx.z;

  // Stage input tile. Rows are contiguous in global (216 floats each).
  const float* inb = in + (size_t)b * kH * kW * kCin;
  const bool interior = (bx0 + kIT <= kW) && (by0 + kIT <= kH);
  if (interior) {
    // float4 path: 1944 16B transfers, fully coalesced, aligned
    // (row base offset = ((gy*512)+bx0)*6 floats, divisible by 4).
    float4* s4 = (float4*)s_in;
    for (int i = t; i < kTotF4; i += 256) {
      int r = i / kRowF4;
      int c4 = i - r * kRowF4;
      const float4* g =
          (const float4*)(inb + ((size_t)(by0 + r) * kW + bx0) * kCin);
      s4[i] = g[c4];
    }
  } else {
    for (int i = t; i < kIT * kRowB; i += 256) {
      int r = i / kRowB;
      int rem = i - r * kRowB;
      int gy = by0 + r;
      int gx = bx0 + rem / kCin;
      float v = 0.f;
      if (gy < kH && gx < kW) v = inb[((size_t)gy * kW + bx0) * kCin + rem];
      s_in[i] = v;
    }
  }
  __syncthreads();

  const int tx = t & 15, ty = t >> 4;

  // Accumulators: 4 pixels x 16 channels, all statically indexed -> VGPRs.
  // Init with bias (uniform scalar load, broadcast).
  float acc[4][16];
#pragma unroll
  for (int p = 0; p < 4; ++p)
#pragma unroll
    for (int o = 0; o < 16; ++o) acc[p][o] = bias[o];

  const int base00 = ty * kRowB + tx * kCin;

#pragma unroll 1
  for (int ky = 0; ky < kFs; ++ky) {
    const int rowb = base00 + ky * kRowB;  // one VALU add per ky
#pragma unroll
    for (int kx = 0; kx < kFs; ++kx) {
#pragma unroll
      for (int cp = 0; cp < 3; ++cp) {
        const int c0 = 2 * cp, c1 = 2 * cp + 1;
        // Wave-uniform weight addresses -> s_load into SGPRs, no LDS.
        const float* w0 = &wd[((ky * kFs + kx) * kCin + c0) * kCout];
        const float* w1 = w0 + kCout;
#pragma unroll
        for (int p = 0; p < 4; ++p) {
          // Two input channels per ds_read_b64 (8B-aligned: index is even).
          const float2 v = *(const float2*)&s_in[rowb + (p >> 1) * (16 * kRowB) +
                                                 ((p & 1) * 16 + kx) * kCin + c0];
          // Only the 10 structurally-nonzero outputs per channel.
#pragma unroll
          for (int j = 0; j < 10; ++j)
            acc[p][kSet[c0][j]] += v.x * w0[kSet[c0][j]];
#pragma unroll
          for (int j = 0; j < 10; ++j)
            acc[p][kSet[c1][j]] += v.y * w1[kSet[c1][j]];
        }
      }
    }
  }

  // Store 4 pixels x 16 channels (64 B per pixel, aligned).
#pragma unroll
  for (int p = 0; p < 4; ++p) {
    int oy = by0 + ty + (p >> 1) * 16;
    int ox = bx0 + tx + (p & 1) * 16;
    if (oy < kOH && ox < kOW) {
      float4* op = (float4*)&out[(((size_t)b * kOH + oy) * kOW + ox) * kCout];
#pragma unroll
      for (int j = 0; j < 4; ++j)
        op[j] = make_float4(acc[p][4 * j + 0], acc[p][4 * j + 1],
                            acc[p][4 * j + 2], acc[p][4 * j + 3]);
    }
  }
}

extern "C" void kernel_launch(void* const* d_in, const int* in_sizes, int n_in,
                              void* d_out, int out_size, void* d_ws, size_t ws_size,
                              hipStream_t stream) {
  const float* in   = (const float*)d_in[0];
  const float* w3   = (const float*)d_in[1];
  const float* w4   = (const float*)d_in[2];
  const float* w44  = (const float*)d_in[3];
  const float* w6   = (const float*)d_in[4];
  const float* bias = (const float*)d_in[5];
  float* out = (float*)d_out;
  float* wd  = (float*)d_ws;  // 2400 floats of scratch

  assemble_weights<<<(kWElems + 255) / 256, 256, 0, stream>>>(w3, w4, w44, w6, wd);

  dim3 grid((kOW + kTile - 1) / kTile, (kOH + kTile - 1) / kTile, kBatch);
  conv_sparse<<<grid, 256, 0, stream>>>(in, wd, bias, out);
}